// Round 17
// baseline (203.988 us; speedup 1.0000x reference)
//
#include <hip/hip_runtime.h>
#include <hip/hip_bf16.h>

#define NTOK 4096   // B*S
#define HD   1024   // hidden
#define DD   2048   // expert hidden
#define NE   8      // experts
#define SLOTS (2*NTOK)

typedef unsigned short u16;
typedef unsigned int   u32;
typedef unsigned long long u64;
typedef __attribute__((ext_vector_type(8))) __bf16 bf16x8;
typedef __attribute__((ext_vector_type(4))) float  f32x4;

__device__ __forceinline__ float bf2f(u16 u) {
    u32 v = ((u32)u) << 16;
    return __uint_as_float(v);
}
__device__ __forceinline__ u16 f2bf(float f) {
    __hip_bfloat16 h = __float2bfloat16(f);   // RTN
    return *reinterpret_cast<u16*>(&h);
}

__device__ __forceinline__ void gload_lds16(const void* g, void* l) {
    __builtin_amdgcn_global_load_lds(
        (__attribute__((address_space(1))) void*)g,
        (__attribute__((address_space(3))) void*)l,
        16, 0, 0);
}

// fast gelu (tanh form): validated r9-r16, absmax unchanged (0.015625)
__device__ __forceinline__ float gelu_f(float v) {
    float x = 0.7978845608028654f * (v + 0.044715f * v * v * v);
    float e = exp2f(x * 2.8853900817779268f);          // e^(2x)
    float th = 1.f - 2.f * __builtin_amdgcn_rcpf(e + 1.f);
    return 0.5f * v * (1.f + th);
}

// ---------------- cvt tile (256 threads): f32 [k][n] -> bf16 [n][k] --------------
// 128k x 64n; thread = 8k x 4n micro-block (r16-proven).
__device__ __forceinline__ void cvt_tile(const float* __restrict__ src,
                                         u16* __restrict__ dst,
                                         int R, int C, int k0, int c0,
                                         u16* tt, int tid) {
    int kg = tid >> 4, ng = tid & 15;
    float4 v[8];
#pragma unroll
    for (int i = 0; i < 8; ++i)
        v[i] = *reinterpret_cast<const float4*>(
            src + (size_t)(k0 + kg * 8 + i) * C + c0 + ng * 4);
    const float* vf = reinterpret_cast<const float*>(v);
#pragma unroll
    for (int j = 0; j < 4; ++j) {
        u16 q8[8];
#pragma unroll
        for (int i = 0; i < 8; ++i) q8[i] = f2bf(vf[i * 4 + j]);
        *reinterpret_cast<uint4*>(&tt[(ng * 4 + j) * 136 + kg * 8]) =
            *reinterpret_cast<uint4*>(q8);
    }
    __syncthreads();
    int nr = tid >> 4, ch = tid & 15;
#pragma unroll
    for (int p = 0; p < 4; ++p) {
        int n = p * 16 + nr;
        uint4 q = *reinterpret_cast<const uint4*>(&tt[n * 136 + ch * 8]);
        *reinterpret_cast<uint4*>(dst + (size_t)(c0 + n) * R + k0 + ch * 8) = q;
    }
}

// ---------------- cvt tile (512 threads): 128k x 128n ----------------------------
// kg=(tid>>4)&15 (8k rows), ng=(tid&15)+((tid>>8)<<4) (4n cols): per-wave bank
// pattern identical to 256-thread version (8 quad-groups x 8 lanes = minimal).
__device__ __forceinline__ void cvt_tile512(const float* __restrict__ src,
                                            u16* __restrict__ dst,
                                            int R, int C, int k0, int c0,
                                            u16* tt, int tid) {
    int kg = (tid >> 4) & 15;
    int ng = (tid & 15) + ((tid >> 8) << 4);
    float4 v[8];
#pragma unroll
    for (int i = 0; i < 8; ++i)
        v[i] = *reinterpret_cast<const float4*>(
            src + (size_t)(k0 + kg * 8 + i) * C + c0 + ng * 4);
    const float* vf = reinterpret_cast<const float*>(v);
#pragma unroll
    for (int j = 0; j < 4; ++j) {
        u16 q8[8];
#pragma unroll
        for (int i = 0; i < 8; ++i) q8[i] = f2bf(vf[i * 4 + j]);
        *reinterpret_cast<uint4*>(&tt[(ng * 4 + j) * 136 + kg * 8]) =
            *reinterpret_cast<uint4*>(q8);
    }
    __syncthreads();
    int nr = tid >> 4, ch = tid & 15;     // 32 rows/pass x 4 passes = 128 rows
#pragma unroll
    for (int p = 0; p < 4; ++p) {
        int n = p * 32 + nr;
        uint4 q = *reinterpret_cast<const uint4*>(&tt[n * 136 + ch * 8]);
        *reinterpret_cast<uint4*>(dst + (size_t)(c0 + n) * R + k0 + ch * 8) = q;
    }
}

// ---------------- prep1: cvt-W1 (2048 blocks) + router (1024 blocks) fused -------
__global__ __launch_bounds__(256) void prep1_k(
        const float* __restrict__ W1, u16* __restrict__ W1t,
        const float* __restrict__ x, const float* __restrict__ gw,
        u16* __restrict__ xb,
        int* __restrict__ counts, float* __restrict__ sum_probs,
        int* __restrict__ tk_idx, float* __restrict__ tk_w) {
    __shared__ __align__(16) u16 tt[64 * 136];
    int bid = blockIdx.x;
    int tid = threadIdx.x;
    if (bid < 2048) {
        int z  = bid >> 8;
        int xq = bid & 255;
        int k0 = (xq >> 5) * 128;
        int c0 = (xq & 31) * 64;
        cvt_tile(W1 + (size_t)z * HD * DD, W1t + (size_t)z * HD * DD,
                 HD, DD, k0, c0, tt, tid);
        return;
    }
    int*   bcnt  = reinterpret_cast<int*>(tt);
    float* bprob = reinterpret_cast<float*>(tt + 32);
    if (tid < NE) { bcnt[tid] = 0; bprob[tid] = 0.f; }
    __syncthreads();

    int gtid = (bid - 2048) * 256 + tid;
    int t    = gtid >> 6;
    int lane = gtid & 63;

    float acc[NE] = {0.f,0.f,0.f,0.f,0.f,0.f,0.f,0.f};
    const float* xr = x + (size_t)t * HD;
    u16* xbr = xb + (size_t)t * HD;
#pragma unroll
    for (int i = 0; i < 4; ++i) {
        int h0 = lane * 4 + i * 256;
        float4 xv4 = *reinterpret_cast<const float4*>(xr + h0);
        u16 xq[4] = {f2bf(xv4.x), f2bf(xv4.y), f2bf(xv4.z), f2bf(xv4.w)};
        *reinterpret_cast<u64*>(xbr + h0) = *reinterpret_cast<u64*>(xq);
        const float xs[4] = {xv4.x, xv4.y, xv4.z, xv4.w};
#pragma unroll
        for (int j = 0; j < 4; ++j) {
            const float4* g = reinterpret_cast<const float4*>(gw + (size_t)(h0 + j) * NE);
            float4 g0 = g[0], g1 = g[1];
            float xv = xs[j];
            acc[0] = fmaf(xv, g0.x, acc[0]); acc[1] = fmaf(xv, g0.y, acc[1]);
            acc[2] = fmaf(xv, g0.z, acc[2]); acc[3] = fmaf(xv, g0.w, acc[3]);
            acc[4] = fmaf(xv, g1.x, acc[4]); acc[5] = fmaf(xv, g1.y, acc[5]);
            acc[6] = fmaf(xv, g1.z, acc[6]); acc[7] = fmaf(xv, g1.w, acc[7]);
        }
    }
#pragma unroll
    for (int off = 32; off >= 1; off >>= 1) {
#pragma unroll
        for (int e = 0; e < NE; ++e) acc[e] += __shfl_xor(acc[e], off);
    }
    float m = acc[0];
#pragma unroll
    for (int e = 1; e < NE; ++e) m = fmaxf(m, acc[e]);
    float p[NE]; float s = 0.f;
#pragma unroll
    for (int e = 0; e < NE; ++e) { p[e] = expf(acc[e] - m); s += p[e]; }
    float inv = 1.f / s;

    int i1 = 0; float v1 = p[0];
#pragma unroll
    for (int e = 1; e < NE; ++e) if (p[e] > v1) { v1 = p[e]; i1 = e; }
    int i2 = -1; float v2 = -1.f;
#pragma unroll
    for (int e = 0; e < NE; ++e) if (e != i1 && p[e] > v2) { v2 = p[e]; i2 = e; }
    float wsum = v1 + v2;

    if (lane < NE) atomicAdd(&bprob[lane], p[lane] * inv);
    if (lane == 0) {
        atomicAdd(&bcnt[i1], 1);
        atomicAdd(&bcnt[i2], 1);
        tk_idx[2 * t]     = i1;  tk_idx[2 * t + 1] = i2;
        tk_w[2 * t]       = v1 / wsum;
        tk_w[2 * t + 1]   = v2 / wsum;
    }
    __syncthreads();
    if (tid < NE) {
        if (bcnt[tid]) atomicAdd(&counts[tid], bcnt[tid]);
        atomicAdd(&sum_probs[tid], bprob[tid]);
    }
}

// ---------------- scatter (scan fused in) -----------------------------------------
__global__ __launch_bounds__(256) void scatter_k(
        const int* __restrict__ tk_idx, const int* __restrict__ counts,
        int* __restrict__ cursor, int* __restrict__ slot_tok,
        int* __restrict__ inv_slot, int* __restrict__ offsets) {
    __shared__ int off[NE];
    if (threadIdx.x == 0) {
        int o = 0;
        for (int e = 0; e < NE; ++e) { off[e] = o; o += counts[e]; }
        if (blockIdx.x == 0)
            for (int e = 0; e < NE; ++e) offsets[e] = off[e];
    }
    __syncthreads();
    int t = blockIdx.x * 256 + threadIdx.x;
    if (t >= NTOK) return;
#pragma unroll
    for (int k = 0; k < 2; ++k) {
        int e = tk_idx[2 * t + k];
        int pos = atomicAdd(&cursor[e], 1);
        int s = off[e] + pos;
        slot_tok[s] = t;
        inv_slot[2 * t + k] = s;
    }
}

// ---------------- GEMM1 (8-wave) + cvt-W2 backfill, one dispatch ------------------
// blocks [0,1152): GEMM 128x128xBK64, 512 thr = 8 waves (2M x 4N, wave tile 64x32),
// XCD-colocated. 4 blocks/CU x 8 waves = 32 waves/CU (the CU thread cap).
// blocks [1152,2176): cvt W2 128x128 tiles (backfill, r16-proven pattern).
__global__ __launch_bounds__(512) void gemm1cvt_k(
        const u16* __restrict__ A,      // xb [NTOK][HD]
        const u16* __restrict__ Bt,     // W1t [NE][DD][HD]
        const float* __restrict__ bias, // b1
        const int* __restrict__ counts, const int* __restrict__ offsets,
        const int* __restrict__ slot_tok,
        u16* __restrict__ outb,         // hbuf
        const float* __restrict__ W2, u16* __restrict__ W2t) {
    __shared__ __align__(16) char smraw[34816];   // max(gemm 33280, cvt 34816)
    int tid = threadIdx.x;

    if (blockIdx.x >= 1152) {
        // cvt W2 [e][2048k][1024n] -> W2t [e][1024n][2048k]; 128 tiles/expert
        int cb = blockIdx.x - 1152;     // 0..1023
        int z  = cb >> 7;
        int xq = cb & 127;
        int k0 = (xq >> 3) * 128;       // 16 k-tiles
        int c0 = (xq & 7) * 128;        // 8 n-tiles
        cvt_tile512(W2 + (size_t)z * DD * HD, W2t + (size_t)z * DD * HD,
                    DD, HD, k0, c0, (u16*)smraw, tid);
        return;
    }

    constexpr int KD = HD, ND = DD;
    u16* As = (u16*)smraw;              // 16 KB
    u16* Bs = As + 128 * 64;            // 16 KB
    int* ids = (int*)(Bs + 128 * 64);   // 512 B

    int xcd = blockIdx.x & 7;
    int s   = blockIdx.x >> 3;      // 0..143
    int mb  = xcd * 9 + (s >> 4);   // 9 panels per XCD
    int nx  = s & 15;
    int e = -1, m0 = 0, accb = 0;
#pragma unroll
    for (int ee = 0; ee < NE; ++ee) {
        int nb = (counts[ee] + 127) >> 7;
        if (e < 0 && mb < accb + nb) { e = ee; m0 = (mb - accb) * 128; }
        accb += nb;
    }
    if (e < 0) return;
    int cnt = counts[e], base = offsets[e];
    int n0 = nx * 128;

    int lane = tid & 63;
    int w    = tid >> 6;            // 8 waves: 2M x 4N, wave tile 64x32
    int wr   = w >> 2, wc = w & 3;
    int lrow = lane & 15, khi = lane >> 4;

    if (tid < 128) ids[tid] = (m0 + tid < cnt) ? slot_tok[base + m0 + tid] : 0;
    __syncthreads();

    const u16* Bte = Bt + (size_t)e * (size_t)ND * KD;
    int srow = tid >> 3;            // 0..63 (staging row within a 64-row round)
    int sslot = tid & 7;

    const u16 *gA[2], *gB[2];
#pragma unroll
    for (int j = 0; j < 2; ++j) {
        int r = j * 64 + srow;
        gA[j] = A   + (size_t)ids[r] * KD    + ((sslot ^ (r & 7)) << 3);
        gB[j] = Bte + (size_t)(n0 + r) * KD  + ((sslot ^ (r & 7)) << 3);
    }

    f32x4 acc[4][2];
#pragma unroll
    for (int m = 0; m < 4; ++m)
#pragma unroll
        for (int n = 0; n < 2; ++n) acc[m][n] = {0.f, 0.f, 0.f, 0.f};

    constexpr int NK = KD / 64;
#pragma unroll 1
    for (int t = 0; t < NK; ++t) {
#pragma unroll
        for (int j = 0; j < 2; ++j) {
            gload_lds16(gA[j] + t * 64, (char*)As + j * 8192 + tid * 16);
            gload_lds16(gB[j] + t * 64, (char*)Bs + j * 8192 + tid * 16);
        }
        __syncthreads();
#pragma unroll
        for (int ks = 0; ks < 2; ++ks) {
            int slot = ks * 4 + khi;
            bf16x8 af[4], bv[2];
#pragma unroll
            for (int m = 0; m < 4; ++m) {
                int r = wr * 64 + m * 16 + lrow;
                af[m] = *reinterpret_cast<const bf16x8*>(
                    &As[r * 64 + ((slot ^ (r & 7)) << 3)]);
            }
#pragma unroll
            for (int n = 0; n < 2; ++n) {
                int r = wc * 32 + n * 16 + lrow;
                bv[n] = *reinterpret_cast<const bf16x8*>(
                    &Bs[r * 64 + ((slot ^ (r & 7)) << 3)]);
            }
            __builtin_amdgcn_s_setprio(1);
#pragma unroll
            for (int m = 0; m < 4; ++m)
#pragma unroll
                for (int n = 0; n < 2; ++n)
                    acc[m][n] = __builtin_amdgcn_mfma_f32_16x16x32_bf16(
                        af[m], bv[n], acc[m][n], 0, 0, 0);
            __builtin_amdgcn_s_setprio(0);
        }
        __syncthreads();
    }

    // epilogue: per-wave 16x40 patch -> coalesced 16B stores (32 cols/wave)
    constexpr int PST = 40;
    u16* patch = As + w * 16 * PST;     // 8 waves x 1280B = 10KB
    float bvals[2];
#pragma unroll
    for (int n = 0; n < 2; ++n)
        bvals[n] = bias[(size_t)e * ND + n0 + wc * 32 + n * 16 + lrow];
#pragma unroll
    for (int m = 0; m < 4; ++m) {
#pragma unroll
        for (int n = 0; n < 2; ++n)
#pragma unroll
            for (int i = 0; i < 4; ++i) {
                float v = acc[m][n][i] + bvals[n];
                v = gelu_f(v);
                patch[(khi * 4 + i) * PST + n * 16 + lrow] = f2bf(v);
            }
        __syncthreads();
        int row = lane >> 2, sl = lane & 3;   // 16 rows x 32 cols in one pass
        uint4 q = *reinterpret_cast<const uint4*>(&patch[row * PST + sl * 8]);
        int grow = m0 + wr * 64 + m * 16 + row;
        if (grow < cnt)
            *reinterpret_cast<uint4*>(
                outb + (size_t)(base + grow) * ND + n0 + wc * 32 + sl * 8) = q;
        __syncthreads();
    }
}

// ---------------- GEMM2: 128x64xBK64, 512 thr = 8 waves (4M x 2N, tile 32x32) ----
__global__ __launch_bounds__(512) void gemm_n64_k(
        const u16* __restrict__ A,      // hbuf [padded][KD]
        const u16* __restrict__ Bt,     // [NE][ND][KD]
        const int* __restrict__ counts, const int* __restrict__ offsets,
        u16* __restrict__ outb, int ND) {
    constexpr int KD = DD;
    int xcd = blockIdx.x & 7;
    int s   = blockIdx.x >> 3;      // 0..143
    int mb  = xcd * 9 + (s >> 4);
    int nx  = s & 15;
    int e = -1, m0 = 0, accb = 0;
#pragma unroll
    for (int ee = 0; ee < NE; ++ee) {
        int nb = (counts[ee] + 127) >> 7;
        if (e < 0 && mb < accb + nb) { e = ee; m0 = (mb - accb) * 128; }
        accb += nb;
    }
    if (e < 0) return;
    int cnt = counts[e], base = offsets[e];
    int n0 = nx * 64;

    __shared__ u16 As[128 * 64];   // 16 KB
    __shared__ u16 Bs[64 * 64];    // 8 KB

    int tid  = threadIdx.x;
    int lane = tid & 63;
    int w    = tid >> 6;            // 8 waves: 4M x 2N, wave tile 32x32
    int wr   = w >> 1, wc = w & 1;
    int lrow = lane & 15, khi = lane >> 4;

    const u16* Bte = Bt + (size_t)e * (size_t)ND * KD;
    int srow = tid >> 3;            // 0..63
    int sslot = tid & 7;

    const u16 *gA[2], *gB;
#pragma unroll
    for (int j = 0; j < 2; ++j) {
        int r = j * 64 + srow;
        gA[j] = A + (size_t)(base + m0 + r) * KD + ((sslot ^ (r & 7)) << 3);
    }
    gB = Bte + (size_t)(n0 + srow) * KD + ((sslot ^ (srow & 7)) << 3);

    f32x4 acc[2][2];
#pragma unroll
    for (int m = 0; m < 2; ++m)
#pragma unroll
        for (int n = 0; n < 2; ++n) acc[m][n] = {0.f, 0.f, 0.f, 0.f};

    constexpr int NK = KD / 64;
#pragma unroll 1
    for (int t = 0; t < NK; ++t) {
#pragma unroll
        for (int j = 0; j < 2; ++j)
            gload_lds16(gA[j] + t * 64, (char*)As + j * 8192 + tid * 16);
        gload_lds16(gB + t * 64, (char*)Bs + tid * 16);
        __syncthreads();
#pragma unroll
        for (int ks = 0; ks < 2; ++ks) {
            int slot = ks * 4 + khi;
            bf16x8 af[2], bv[2];
#pragma unroll
            for (int m = 0; m < 2; ++m) {
                int r = wr * 32 + m * 16 + lrow;
                af[m] = *reinterpret_cast<const bf16x8*>(
                    &As[r * 64 + ((slot ^ (r & 7)) << 3)]);
            }
#pragma unroll
            for (int n = 0; n < 2; ++n) {
                int r = wc * 32 + n * 16 + lrow;
                bv[n] = *reinterpret_cast<const bf16x8*>(
                    &Bs[r * 64 + ((slot ^ (r & 7)) << 3)]);
            }
            __builtin_amdgcn_s_setprio(1);
#pragma unroll
            for (int m = 0; m < 2; ++m)
#pragma unroll
                for (int n = 0; n < 2; ++n)
                    acc[m][n] = __builtin_amdgcn_mfma_f32_16x16x32_bf16(
                        af[m], bv[n], acc[m][n], 0, 0, 0);
            __builtin_amdgcn_s_setprio(0);
        }
        __syncthreads();
    }

    // epilogue: per-wave 16x40 patch -> coalesced 16B stores (32 cols/wave)
    constexpr int PST = 40;
    u16* patch = As + w * 16 * PST;
#pragma unroll
    for (int m = 0; m < 2; ++m) {
#pragma unroll
        for (int n = 0; n < 2; ++n)
#pragma unroll
            for (int i = 0; i < 4; ++i)
                patch[(khi * 4 + i) * PST + n * 16 + lrow] = f2bf(acc[m][n][i]);
        __syncthreads();
        int row = lane >> 2, sl = lane & 3;   // 16 rows x 32 cols in one pass
        uint4 q = *reinterpret_cast<const uint4*>(&patch[row * PST + sl * 8]);
        int grow = m0 + wr * 32 + m * 16 + row;
        if (grow < cnt)
            *reinterpret_cast<uint4*>(
                outb + (size_t)(base + grow) * ND + n0 + wc * 32 + sl * 8) = q;
        __syncthreads();
    }
}

// ---------------- combine (+aux finalize fused) -----------------------------------
__global__ __launch_bounds__(256) void combine_k(
        const int* __restrict__ tk_idx, const float* __restrict__ tk_w,
        const int* __restrict__ inv_slot, const u16* __restrict__ ybuf,
        const float* __restrict__ b2, float* __restrict__ out,
        const int* __restrict__ counts, const float* __restrict__ sum_probs,
        float* __restrict__ out_aux) {
    if (blockIdx.x == 0 && threadIdx.x == 0) {
        double s = 0.0;
        for (int e = 0; e < NE; ++e) s += (double)counts[e] * (double)sum_probs[e];
        out_aux[0] = (float)(s * (8.0 / (2.0 * (double)NTOK)));
    }
    int gtid = blockIdx.x * 256 + threadIdx.x;
    int t = gtid >> 6;
    int lane = gtid & 63;
    int e0 = tk_idx[2 * t], e1 = tk_idx[2 * t + 1];
    float w0 = tk_w[2 * t], w1 = tk_w[2 * t + 1];
    int s0 = inv_slot[2 * t], s1 = inv_slot[2 * t + 1];

#pragma unroll
    for (int i = 0; i < 2; ++i) {
        int c = lane * 8 + i * 512;
        uint4 q0 = *reinterpret_cast<const uint4*>(ybuf + (size_t)s0 * HD + c);
        uint4 q1 = *reinterpret_cast<const uint4*>(ybuf + (size_t)s1 * HD + c);
        float y0[8] = {bf2f((u16)(q0.x&0xffff)), bf2f((u16)(q0.x>>16)),
                       bf2f((u16)(q0.y&0xffff)), bf2f((u16)(q0.y>>16)),
                       bf2f((u16)(q0.z&0xffff)), bf2f((u16)(q0.z>>16)),
                       bf2f((u16)(q0.w&0xffff)), bf2f((u16)(q0.w>>16))};
        float y1[8] = {bf2f((u16)(q1.x&0xffff)), bf2f((u16)(q1.x>>16)),
                       bf2f((u16)(q1.y&0xffff)), bf2f((u16)(q1.y>>16)),
                       bf2f((u16)(q1.z&0xffff)), bf2f((u16)(q1.z>>16)),
                       bf2f((u16)(q1.w&0xffff)), bf2f((u16)(q1.w>>16))};
        float r[8];
#pragma unroll
        for (int j = 0; j < 8; ++j) {
            float v0 = y0[j] + b2[e0 * HD + c + j];
            float v1 = y1[j] + b2[e1 * HD + c + j];
            r[j] = w0 * v0 + w1 * v1;
        }
        float* op = out + (size_t)t * HD + c;
        *reinterpret_cast<float4*>(op)     = make_float4(r[0], r[1], r[2], r[3]);
        *reinterpret_cast<float4*>(op + 4) = make_float4(r[4], r[5], r[6], r[7]);
    }
}

extern "C" void kernel_launch(void* const* d_in, const int* in_sizes, int n_in,
                              void* d_out, int out_size, void* d_ws, size_t ws_size,
                              hipStream_t stream) {
    const float* x   = (const float*)d_in[0];
    const float* gw  = (const float*)d_in[1];
    const float* W1  = (const float*)d_in[2];
    const float* b1  = (const float*)d_in[3];
    const float* W2  = (const float*)d_in[4];
    const float* b2  = (const float*)d_in[5];
    float* out = (float*)d_out;

    char* ws = (char*)d_ws;
    // meta block [0,512): counts@0, cursor@32, offsets@64, sum_probs@128
    int*   counts    = (int*)(ws + 0);
    int*   cursor    = (int*)(ws + 32);
    int*   offsets   = (int*)(ws + 64);
    float* sum_probs = (float*)(ws + 128);
    int*   tk_idx    = (int*)(ws + 512);                 // 32768 B
    float* tk_w      = (float*)(ws + 33280);             // 32768 B
    int*   slot_tok  = (int*)(ws + 66048);               // 32768 B
    int*   inv_slot  = (int*)(ws + 98816);               // 32768 B
    u16*   xb        = (u16*)(ws + 131584);              // 8,388,608 B
    u16*   W1t       = (u16*)(ws + 8520192);             // 33,554,432 B [ybuf aliases]
    u16*   W2t       = (u16*)(ws + 42074624);            // 33,554,432 B
    u16*   hbuf      = (u16*)(ws + 75629056);            // 34,078,720 B (8320 rows)
    u16*   ybuf      = W1t;                              // W1t dead after gemm1
    // total = 109,707,776 B

    hipMemsetAsync(ws, 0, 512, stream);

    // prep1: cvt-W1 (2048 blocks) + router (1024 blocks)
    prep1_k<<<2048 + 1024, 256, 0, stream>>>(W1, W1t, x, gw, xb,
                                             counts, sum_probs, tk_idx, tk_w);
    scatter_k<<<NTOK / 256, 256, 0, stream>>>(tk_idx, counts, cursor,
                                              slot_tok, inv_slot, offsets);

    // GEMM1 8-wave (1152 XCD-colocated blocks) + cvt-W2 backfill (1024 blocks)
    gemm1cvt_k<<<1152 + 1024, 512, 0, stream>>>(
        xb, W1t, b1, counts, offsets, slot_tok, hbuf, W2, W2t);
    // GEMM2 8-wave: 128x64, 1152 blocks XCD-colocated
    gemm_n64_k<<<1152, 512, 0, stream>>>(
        hbuf, W2t, counts, offsets, ybuf, HD);

    combine_k<<<NTOK / 4, 256, 0, stream>>>(tk_idx, tk_w, inv_slot, ybuf, b2, out,
                                            counts, sum_probs,
                                            out + (size_t)NTOK * HD);
}

// Round 18
// 198.811 us; speedup vs baseline: 1.0260x; 1.0260x over previous
//
#include <hip/hip_runtime.h>
#include <hip/hip_bf16.h>

#define NTOK 4096   // B*S
#define HD   1024   // hidden
#define DD   2048   // expert hidden
#define NE   8      // experts
#define SLOTS (2*NTOK)

typedef unsigned short u16;
typedef unsigned int   u32;
typedef unsigned long long u64;
typedef __attribute__((ext_vector_type(8))) __bf16 bf16x8;
typedef __attribute__((ext_vector_type(4))) float  f32x4;

__device__ __forceinline__ float bf2f(u16 u) {
    u32 v = ((u32)u) << 16;
    return __uint_as_float(v);
}
__device__ __forceinline__ u16 f2bf(float f) {
    __hip_bfloat16 h = __float2bfloat16(f);   // RTN
    return *reinterpret_cast<u16*>(&h);
}

__device__ __forceinline__ void gload_lds16(const void* g, void* l) {
    __builtin_amdgcn_global_load_lds(
        (__attribute__((address_space(1))) void*)g,
        (__attribute__((address_space(3))) void*)l,
        16, 0, 0);
}

// fast gelu (tanh form): validated r9-r17, absmax unchanged (0.015625)
__device__ __forceinline__ float gelu_f(float v) {
    float x = 0.7978845608028654f * (v + 0.044715f * v * v * v);
    float e = exp2f(x * 2.8853900817779268f);          // e^(2x)
    float th = 1.f - 2.f * __builtin_amdgcn_rcpf(e + 1.f);
    return 0.5f * v * (1.f + th);
}

// ---------------- cvt tile (256 threads): f32 [k][n] -> bf16 [n][k] --------------
__device__ __forceinline__ void cvt_tile(const float* __restrict__ src,
                                         u16* __restrict__ dst,
                                         int R, int C, int k0, int c0,
                                         u16* tt, int tid) {
    int kg = tid >> 4, ng = tid & 15;
    float4 v[8];
#pragma unroll
    for (int i = 0; i < 8; ++i)
        v[i] = *reinterpret_cast<const float4*>(
            src + (size_t)(k0 + kg * 8 + i) * C + c0 + ng * 4);
    const float* vf = reinterpret_cast<const float*>(v);
#pragma unroll
    for (int j = 0; j < 4; ++j) {
        u16 q8[8];
#pragma unroll
        for (int i = 0; i < 8; ++i) q8[i] = f2bf(vf[i * 4 + j]);
        *reinterpret_cast<uint4*>(&tt[(ng * 4 + j) * 136 + kg * 8]) =
            *reinterpret_cast<uint4*>(q8);
    }
    __syncthreads();
    int nr = tid >> 4, ch = tid & 15;
#pragma unroll
    for (int p = 0; p < 4; ++p) {
        int n = p * 16 + nr;
        uint4 q = *reinterpret_cast<const uint4*>(&tt[n * 136 + ch * 8]);
        *reinterpret_cast<uint4*>(dst + (size_t)(c0 + n) * R + k0 + ch * 8) = q;
    }
}

// ---------------- cvt tile (512 threads): 128k x 128n ----------------------------
__device__ __forceinline__ void cvt_tile512(const float* __restrict__ src,
                                            u16* __restrict__ dst,
                                            int R, int C, int k0, int c0,
                                            u16* tt, int tid) {
    int kg = (tid >> 4) & 15;
    int ng = (tid & 15) + ((tid >> 8) << 4);
    float4 v[8];
#pragma unroll
    for (int i = 0; i < 8; ++i)
        v[i] = *reinterpret_cast<const float4*>(
            src + (size_t)(k0 + kg * 8 + i) * C + c0 + ng * 4);
    const float* vf = reinterpret_cast<const float*>(v);
#pragma unroll
    for (int j = 0; j < 4; ++j) {
        u16 q8[8];
#pragma unroll
        for (int i = 0; i < 8; ++i) q8[i] = f2bf(vf[i * 4 + j]);
        *reinterpret_cast<uint4*>(&tt[(ng * 4 + j) * 136 + kg * 8]) =
            *reinterpret_cast<uint4*>(q8);
    }
    __syncthreads();
    int nr = tid >> 4, ch = tid & 15;     // 32 rows/pass x 4 passes = 128 rows
#pragma unroll
    for (int p = 0; p < 4; ++p) {
        int n = p * 32 + nr;
        uint4 q = *reinterpret_cast<const uint4*>(&tt[n * 136 + ch * 8]);
        *reinterpret_cast<uint4*>(dst + (size_t)(c0 + n) * R + k0 + ch * 8) = q;
    }
}

// ---------------- prep1: cvt-W1 (2048 blocks) + router (1024 blocks) fused -------
__global__ __launch_bounds__(256) void prep1_k(
        const float* __restrict__ W1, u16* __restrict__ W1t,
        const float* __restrict__ x, const float* __restrict__ gw,
        u16* __restrict__ xb,
        int* __restrict__ counts, float* __restrict__ sum_probs,
        int* __restrict__ tk_idx, float* __restrict__ tk_w) {
    __shared__ __align__(16) u16 tt[64 * 136];
    int bid = blockIdx.x;
    int tid = threadIdx.x;
    if (bid < 2048) {
        int z  = bid >> 8;
        int xq = bid & 255;
        int k0 = (xq >> 5) * 128;
        int c0 = (xq & 31) * 64;
        cvt_tile(W1 + (size_t)z * HD * DD, W1t + (size_t)z * HD * DD,
                 HD, DD, k0, c0, tt, tid);
        return;
    }
    int*   bcnt  = reinterpret_cast<int*>(tt);
    float* bprob = reinterpret_cast<float*>(tt + 32);
    if (tid < NE) { bcnt[tid] = 0; bprob[tid] = 0.f; }
    __syncthreads();

    int gtid = (bid - 2048) * 256 + tid;
    int t    = gtid >> 6;
    int lane = gtid & 63;

    float acc[NE] = {0.f,0.f,0.f,0.f,0.f,0.f,0.f,0.f};
    const float* xr = x + (size_t)t * HD;
    u16* xbr = xb + (size_t)t * HD;
#pragma unroll
    for (int i = 0; i < 4; ++i) {
        int h0 = lane * 4 + i * 256;
        float4 xv4 = *reinterpret_cast<const float4*>(xr + h0);
        u16 xq[4] = {f2bf(xv4.x), f2bf(xv4.y), f2bf(xv4.z), f2bf(xv4.w)};
        *reinterpret_cast<u64*>(xbr + h0) = *reinterpret_cast<u64*>(xq);
        const float xs[4] = {xv4.x, xv4.y, xv4.z, xv4.w};
#pragma unroll
        for (int j = 0; j < 4; ++j) {
            const float4* g = reinterpret_cast<const float4*>(gw + (size_t)(h0 + j) * NE);
            float4 g0 = g[0], g1 = g[1];
            float xv = xs[j];
            acc[0] = fmaf(xv, g0.x, acc[0]); acc[1] = fmaf(xv, g0.y, acc[1]);
            acc[2] = fmaf(xv, g0.z, acc[2]); acc[3] = fmaf(xv, g0.w, acc[3]);
            acc[4] = fmaf(xv, g1.x, acc[4]); acc[5] = fmaf(xv, g1.y, acc[5]);
            acc[6] = fmaf(xv, g1.z, acc[6]); acc[7] = fmaf(xv, g1.w, acc[7]);
        }
    }
#pragma unroll
    for (int off = 32; off >= 1; off >>= 1) {
#pragma unroll
        for (int e = 0; e < NE; ++e) acc[e] += __shfl_xor(acc[e], off);
    }
    float m = acc[0];
#pragma unroll
    for (int e = 1; e < NE; ++e) m = fmaxf(m, acc[e]);
    float p[NE]; float s = 0.f;
#pragma unroll
    for (int e = 0; e < NE; ++e) { p[e] = expf(acc[e] - m); s += p[e]; }
    float inv = 1.f / s;

    int i1 = 0; float v1 = p[0];
#pragma unroll
    for (int e = 1; e < NE; ++e) if (p[e] > v1) { v1 = p[e]; i1 = e; }
    int i2 = -1; float v2 = -1.f;
#pragma unroll
    for (int e = 0; e < NE; ++e) if (e != i1 && p[e] > v2) { v2 = p[e]; i2 = e; }
    float wsum = v1 + v2;

    if (lane < NE) atomicAdd(&bprob[lane], p[lane] * inv);
    if (lane == 0) {
        atomicAdd(&bcnt[i1], 1);
        atomicAdd(&bcnt[i2], 1);
        tk_idx[2 * t]     = i1;  tk_idx[2 * t + 1] = i2;
        tk_w[2 * t]       = v1 / wsum;
        tk_w[2 * t + 1]   = v2 / wsum;
    }
    __syncthreads();
    if (tid < NE) {
        if (bcnt[tid]) atomicAdd(&counts[tid], bcnt[tid]);
        atomicAdd(&sum_probs[tid], bprob[tid]);
    }
}

// ---------------- scatter (scan fused in) -----------------------------------------
__global__ __launch_bounds__(256) void scatter_k(
        const int* __restrict__ tk_idx, const int* __restrict__ counts,
        int* __restrict__ cursor, int* __restrict__ slot_tok,
        int* __restrict__ inv_slot, int* __restrict__ offsets) {
    __shared__ int off[NE];
    if (threadIdx.x == 0) {
        int o = 0;
        for (int e = 0; e < NE; ++e) { off[e] = o; o += counts[e]; }
        if (blockIdx.x == 0)
            for (int e = 0; e < NE; ++e) offsets[e] = off[e];
    }
    __syncthreads();
    int t = blockIdx.x * 256 + threadIdx.x;
    if (t >= NTOK) return;
#pragma unroll
    for (int k = 0; k < 2; ++k) {
        int e = tk_idx[2 * t + k];
        int pos = atomicAdd(&cursor[e], 1);
        int s = off[e] + pos;
        slot_tok[s] = t;
        inv_slot[2 * t + k] = s;
    }
}

// ---------------- GEMM1 (8-wave, r17-proven) + cvt-W2 backfill, one dispatch -----
__global__ __launch_bounds__(512) void gemm1cvt_k(
        const u16* __restrict__ A,      // xb [NTOK][HD]
        const u16* __restrict__ Bt,     // W1t [NE][DD][HD]
        const float* __restrict__ bias, // b1
        const int* __restrict__ counts, const int* __restrict__ offsets,
        const int* __restrict__ slot_tok,
        u16* __restrict__ outb,         // hbuf
        const float* __restrict__ W2, u16* __restrict__ W2t) {
    __shared__ __align__(16) char smraw[34816];
    int tid = threadIdx.x;

    if (blockIdx.x >= 1152) {
        int cb = blockIdx.x - 1152;     // 0..1023
        int z  = cb >> 7;
        int xq = cb & 127;
        int k0 = (xq >> 3) * 128;
        int c0 = (xq & 7) * 128;
        cvt_tile512(W2 + (size_t)z * DD * HD, W2t + (size_t)z * DD * HD,
                    DD, HD, k0, c0, (u16*)smraw, tid);
        return;
    }

    constexpr int KD = HD, ND = DD;
    u16* As = (u16*)smraw;              // 16 KB
    u16* Bs = As + 128 * 64;            // 16 KB
    int* ids = (int*)(Bs + 128 * 64);   // 512 B

    int xcd = blockIdx.x & 7;
    int s   = blockIdx.x >> 3;      // 0..143
    int mb  = xcd * 9 + (s >> 4);
    int nx  = s & 15;
    int e = -1, m0 = 0, accb = 0;
#pragma unroll
    for (int ee = 0; ee < NE; ++ee) {
        int nb = (counts[ee] + 127) >> 7;
        if (e < 0 && mb < accb + nb) { e = ee; m0 = (mb - accb) * 128; }
        accb += nb;
    }
    if (e < 0) return;
    int cnt = counts[e], base = offsets[e];
    int n0 = nx * 128;

    int lane = tid & 63;
    int w    = tid >> 6;            // 8 waves: 2M x 4N, wave tile 64x32
    int wr   = w >> 2, wc = w & 3;
    int lrow = lane & 15, khi = lane >> 4;

    if (tid < 128) ids[tid] = (m0 + tid < cnt) ? slot_tok[base + m0 + tid] : 0;
    __syncthreads();

    const u16* Bte = Bt + (size_t)e * (size_t)ND * KD;
    int srow = tid >> 3;            // 0..63
    int sslot = tid & 7;

    const u16 *gA[2], *gB[2];
#pragma unroll
    for (int j = 0; j < 2; ++j) {
        int r = j * 64 + srow;
        gA[j] = A   + (size_t)ids[r] * KD    + ((sslot ^ (r & 7)) << 3);
        gB[j] = Bte + (size_t)(n0 + r) * KD  + ((sslot ^ (r & 7)) << 3);
    }

    f32x4 acc[4][2];
#pragma unroll
    for (int m = 0; m < 4; ++m)
#pragma unroll
        for (int n = 0; n < 2; ++n) acc[m][n] = {0.f, 0.f, 0.f, 0.f};

    constexpr int NK = KD / 64;
#pragma unroll 1
    for (int t = 0; t < NK; ++t) {
#pragma unroll
        for (int j = 0; j < 2; ++j) {
            gload_lds16(gA[j] + t * 64, (char*)As + j * 8192 + tid * 16);
            gload_lds16(gB[j] + t * 64, (char*)Bs + j * 8192 + tid * 16);
        }
        __syncthreads();
#pragma unroll
        for (int ks = 0; ks < 2; ++ks) {
            int slot = ks * 4 + khi;
            bf16x8 af[4], bv[2];
#pragma unroll
            for (int m = 0; m < 4; ++m) {
                int r = wr * 64 + m * 16 + lrow;
                af[m] = *reinterpret_cast<const bf16x8*>(
                    &As[r * 64 + ((slot ^ (r & 7)) << 3)]);
            }
#pragma unroll
            for (int n = 0; n < 2; ++n) {
                int r = wc * 32 + n * 16 + lrow;
                bv[n] = *reinterpret_cast<const bf16x8*>(
                    &Bs[r * 64 + ((slot ^ (r & 7)) << 3)]);
            }
            __builtin_amdgcn_s_setprio(1);
#pragma unroll
            for (int m = 0; m < 4; ++m)
#pragma unroll
                for (int n = 0; n < 2; ++n)
                    acc[m][n] = __builtin_amdgcn_mfma_f32_16x16x32_bf16(
                        af[m], bv[n], acc[m][n], 0, 0, 0);
            __builtin_amdgcn_s_setprio(0);
        }
        __syncthreads();
    }

    constexpr int PST = 40;
    u16* patch = As + w * 16 * PST;     // 8 waves x 1280B = 10KB
    float bvals[2];
#pragma unroll
    for (int n = 0; n < 2; ++n)
        bvals[n] = bias[(size_t)e * ND + n0 + wc * 32 + n * 16 + lrow];
#pragma unroll
    for (int m = 0; m < 4; ++m) {
#pragma unroll
        for (int n = 0; n < 2; ++n)
#pragma unroll
            for (int i = 0; i < 4; ++i) {
                float v = acc[m][n][i] + bvals[n];
                v = gelu_f(v);
                patch[(khi * 4 + i) * PST + n * 16 + lrow] = f2bf(v);
            }
        __syncthreads();
        int row = lane >> 2, sl = lane & 3;
        uint4 q = *reinterpret_cast<const uint4*>(&patch[row * PST + sl * 8]);
        int grow = m0 + wr * 64 + m * 16 + row;
        if (grow < cnt)
            *reinterpret_cast<uint4*>(
                outb + (size_t)(base + grow) * ND + n0 + wc * 32 + sl * 8) = q;
        __syncthreads();
    }
}

// ---------------- GEMM2 (r16-proven): 128x64xBK64, 256 thr / 4 waves -------------
template<int KD>
__global__ __launch_bounds__(256) void gemm_n64_k(
        const u16* __restrict__ A,      // hbuf [padded][KD]
        const u16* __restrict__ Bt,     // [NE][ND][KD]
        const int* __restrict__ counts, const int* __restrict__ offsets,
        u16* __restrict__ outb, int ND) {
    int xcd = blockIdx.x & 7;
    int s   = blockIdx.x >> 3;      // 0..143
    int mb  = xcd * 9 + (s >> 4);
    int nx  = s & 15;
    int e = -1, m0 = 0, accb = 0;
#pragma unroll
    for (int ee = 0; ee < NE; ++ee) {
        int nb = (counts[ee] + 127) >> 7;
        if (e < 0 && mb < accb + nb) { e = ee; m0 = (mb - accb) * 128; }
        accb += nb;
    }
    if (e < 0) return;
    int cnt = counts[e], base = offsets[e];
    int n0 = nx * 64;

    __shared__ u16 As[128 * 64];   // 16 KB
    __shared__ u16 Bs[64 * 64];    // 8 KB

    int tid  = threadIdx.x;
    int lane = tid & 63;
    int w    = tid >> 6;            // 4 waves, 2M x 2N; wave tile 64x32
    int wr   = w >> 1, wc = w & 1;
    int lrow = lane & 15, khi = lane >> 4;

    const u16* Bte = Bt + (size_t)e * (size_t)ND * KD;
    int srow = tid >> 3;            // 0..31
    int sslot = tid & 7;

    const u16 *gA[4], *gB[2];
#pragma unroll
    for (int j = 0; j < 4; ++j) {
        int r = j * 32 + srow;
        gA[j] = A + (size_t)(base + m0 + r) * KD + ((sslot ^ (r & 7)) << 3);
    }
#pragma unroll
    for (int j = 0; j < 2; ++j) {
        int r = j * 32 + srow;
        gB[j] = Bte + (size_t)(n0 + r) * KD + ((sslot ^ (r & 7)) << 3);
    }

    f32x4 acc[4][2];
#pragma unroll
    for (int m = 0; m < 4; ++m)
#pragma unroll
        for (int n = 0; n < 2; ++n) acc[m][n] = {0.f, 0.f, 0.f, 0.f};

    constexpr int NK = KD / 64;
#pragma unroll 1
    for (int t = 0; t < NK; ++t) {
#pragma unroll
        for (int j = 0; j < 4; ++j)
            gload_lds16(gA[j] + t * 64, (char*)As + j * 4096 + tid * 16);
#pragma unroll
        for (int j = 0; j < 2; ++j)
            gload_lds16(gB[j] + t * 64, (char*)Bs + j * 4096 + tid * 16);
        __syncthreads();
#pragma unroll
        for (int ks = 0; ks < 2; ++ks) {
            int slot = ks * 4 + khi;
            bf16x8 af[4], bv[2];
#pragma unroll
            for (int m = 0; m < 4; ++m) {
                int r = wr * 64 + m * 16 + lrow;
                af[m] = *reinterpret_cast<const bf16x8*>(
                    &As[r * 64 + ((slot ^ (r & 7)) << 3)]);
            }
#pragma unroll
            for (int n = 0; n < 2; ++n) {
                int r = wc * 32 + n * 16 + lrow;
                bv[n] = *reinterpret_cast<const bf16x8*>(
                    &Bs[r * 64 + ((slot ^ (r & 7)) << 3)]);
            }
            __builtin_amdgcn_s_setprio(1);
#pragma unroll
            for (int m = 0; m < 4; ++m)
#pragma unroll
                for (int n = 0; n < 2; ++n)
                    acc[m][n] = __builtin_amdgcn_mfma_f32_16x16x32_bf16(
                        af[m], bv[n], acc[m][n], 0, 0, 0);
            __builtin_amdgcn_s_setprio(0);
        }
        __syncthreads();
    }

    // epilogue: per-wave 16x40 patch -> coalesced stores (32 cols per wave)
    constexpr int PST = 40;
    u16* patch = As + w * 16 * PST;
#pragma unroll
    for (int m = 0; m < 4; ++m) {
#pragma unroll
        for (int n = 0; n < 2; ++n)
#pragma unroll
            for (int i = 0; i < 4; ++i)
                patch[(khi * 4 + i) * PST + n * 16 + lrow] = f2bf(acc[m][n][i]);
        __syncthreads();
        int row = lane >> 2, sl = lane & 3;   // 16 rows x 32 cols in one pass
        uint4 q = *reinterpret_cast<const uint4*>(&patch[row * PST + sl * 8]);
        int grow = m0 + wr * 64 + m * 16 + row;
        if (grow < cnt)
            *reinterpret_cast<uint4*>(
                outb + (size_t)(base + grow) * ND + n0 + wc * 32 + sl * 8) = q;
        __syncthreads();
    }
}

// ---------------- combine (+aux finalize fused) -----------------------------------
__global__ __launch_bounds__(256) void combine_k(
        const int* __restrict__ tk_idx, const float* __restrict__ tk_w,
        const int* __restrict__ inv_slot, const u16* __restrict__ ybuf,
        const float* __restrict__ b2, float* __restrict__ out,
        const int* __restrict__ counts, const float* __restrict__ sum_probs,
        float* __restrict__ out_aux) {
    if (blockIdx.x == 0 && threadIdx.x == 0) {
        double s = 0.0;
        for (int e = 0; e < NE; ++e) s += (double)counts[e] * (double)sum_probs[e];
        out_aux[0] = (float)(s * (8.0 / (2.0 * (double)NTOK)));
    }
    int gtid = blockIdx.x * 256 + threadIdx.x;
    int t = gtid >> 6;
    int lane = gtid & 63;
    int e0 = tk_idx[2 * t], e1 = tk_idx[2 * t + 1];
    float w0 = tk_w[2 * t], w1 = tk_w[2 * t + 1];
    int s0 = inv_slot[2 * t], s1 = inv_slot[2 * t + 1];

#pragma unroll
    for (int i = 0; i < 2; ++i) {
        int c = lane * 8 + i * 512;
        uint4 q0 = *reinterpret_cast<const uint4*>(ybuf + (size_t)s0 * HD + c);
        uint4 q1 = *reinterpret_cast<const uint4*>(ybuf + (size_t)s1 * HD + c);
        float y0[8] = {bf2f((u16)(q0.x&0xffff)), bf2f((u16)(q0.x>>16)),
                       bf2f((u16)(q0.y&0xffff)), bf2f((u16)(q0.y>>16)),
                       bf2f((u16)(q0.z&0xffff)), bf2f((u16)(q0.z>>16)),
                       bf2f((u16)(q0.w&0xffff)), bf2f((u16)(q0.w>>16))};
        float y1[8] = {bf2f((u16)(q1.x&0xffff)), bf2f((u16)(q1.x>>16)),
                       bf2f((u16)(q1.y&0xffff)), bf2f((u16)(q1.y>>16)),
                       bf2f((u16)(q1.z&0xffff)), bf2f((u16)(q1.z>>16)),
                       bf2f((u16)(q1.w&0xffff)), bf2f((u16)(q1.w>>16))};
        float r[8];
#pragma unroll
        for (int j = 0; j < 8; ++j) {
            float v0 = y0[j] + b2[e0 * HD + c + j];
            float v1 = y1[j] + b2[e1 * HD + c + j];
            r[j] = w0 * v0 + w1 * v1;
        }
        float* op = out + (size_t)t * HD + c;
        *reinterpret_cast<float4*>(op)     = make_float4(r[0], r[1], r[2], r[3]);
        *reinterpret_cast<float4*>(op + 4) = make_float4(r[4], r[5], r[6], r[7]);
    }
}

extern "C" void kernel_launch(void* const* d_in, const int* in_sizes, int n_in,
                              void* d_out, int out_size, void* d_ws, size_t ws_size,
                              hipStream_t stream) {
    const float* x   = (const float*)d_in[0];
    const float* gw  = (const float*)d_in[1];
    const float* W1  = (const float*)d_in[2];
    const float* b1  = (const float*)d_in[3];
    const float* W2  = (const float*)d_in[4];
    const float* b2  = (const float*)d_in[5];
    float* out = (float*)d_out;

    char* ws = (char*)d_ws;
    // meta block [0,512): counts@0, cursor@32, offsets@64, sum_probs@128
    int*   counts    = (int*)(ws + 0);
    int*   cursor    = (int*)(ws + 32);
    int*   offsets   = (int*)(ws + 64);
    float* sum_probs = (float*)(ws + 128);
    int*   tk_idx    = (int*)(ws + 512);                 // 32768 B
    float* tk_w      = (float*)(ws + 33280);             // 32768 B
    int*   slot_tok  = (int*)(ws + 66048);               // 32768 B
    int*   inv_slot  = (int*)(ws + 98816);               // 32768 B
    u16*   xb        = (u16*)(ws + 131584);              // 8,388,608 B
    u16*   W1t       = (u16*)(ws + 8520192);             // 33,554,432 B [ybuf aliases]
    u16*   W2t       = (u16*)(ws + 42074624);            // 33,554,432 B
    u16*   hbuf      = (u16*)(ws + 75629056);            // 34,078,720 B (8320 rows)
    u16*   ybuf      = W1t;                              // W1t dead after gemm1
    // total = 109,707,776 B

    hipMemsetAsync(ws, 0, 512, stream);

    // prep1: cvt-W1 (2048 blocks) + router (1024 blocks)
    prep1_k<<<2048 + 1024, 256, 0, stream>>>(W1, W1t, x, gw, xb,
                                             counts, sum_probs, tk_idx, tk_w);
    scatter_k<<<NTOK / 256, 256, 0, stream>>>(tk_idx, counts, cursor,
                                              slot_tok, inv_slot, offsets);

    // GEMM1 8-wave (1152 XCD-colocated blocks) + cvt-W2 backfill (1024 blocks)
    gemm1cvt_k<<<1152 + 1024, 512, 0, stream>>>(
        xb, W1t, b1, counts, offsets, slot_tok, hbuf, W2, W2t);
    // GEMM2 4-wave (r16-proven): 128x64, 1152 blocks XCD-colocated
    gemm_n64_k<DD><<<1152, 256, 0, stream>>>(
        hbuf, W2t, counts, offsets, ybuf, HD);

    combine_k<<<NTOK / 4, 256, 0, stream>>>(tk_idx, tk_w, inv_slot, ybuf, b2, out,
                                            counts, sum_probs,
                                            out + (size_t)NTOK * HD);
}